// Round 9
// baseline (154.242 us; speedup 1.0000x reference)
//
#include <hip/hip_runtime.h>
#include <hip/hip_bf16.h>

typedef __attribute__((ext_vector_type(4))) float f32x4;
typedef __attribute__((ext_vector_type(4))) unsigned int u32x4;
typedef __attribute__((ext_vector_type(8))) short bf16x8;

__device__ __forceinline__ short f2bf(float f) {
  __hip_bfloat16 h = __float2bfloat16(f);
  return __builtin_bit_cast(short, h);
}

// ---------------------------------------------------------------------------
// GEMM view: C[8192 x 512] = A[8192 x 1024] * B[1024 x 512], k = j*4 + kc,
// kc -> x component {0,1,2,4}.  512 cols = [c0 of i=0..255 | c4 of i=0..255].
// Halved-B redundancy trick (R8, verified): c0 frag per j = [w0,w1,w2,0];
// c4 frag = [0,w2,-w1,w0] built in-register from the c0 frag (6 VALU ops).
// Bp stores ONLY the c0 half: Bp[it=0..31][cg=0..15][lane][8 shorts] = 512KB.
//
// THIS ROUND: elasticity. The only ~6.2 TB/s kernels measured on this
// machine (harness fills, R4 prep_A) are many small INDEPENDENT blocks.
// Every ~43us variant was one fat 16-wave lockstep block per CU. So:
// 3 passes, all barrier-free, 256-thread blocks, >=6 blocks/CU.
// ---------------------------------------------------------------------------
__global__ __launch_bounds__(256) void ga_prep_B(const float* __restrict__ W,
                                                 short* __restrict__ Bp) {
  const int gid = blockIdx.x * 256 + threadIdx.x;  // 32768 = 32 it * 16 cg * 64 lane
  const int l  = gid & 63;
  const int cg = (gid >> 6) & 15;
  const int it = gid >> 10;
  const int ln = l & 15, q = l >> 4;
  const int i  = cg * 16 + ln;
  const int j0 = it * 8 + q * 2;
  const float4* W4 = (const float4*)W;

  bf16x8 o;
#pragma unroll
  for (int jj = 0; jj < 2; ++jj) {
    const float4 wv = W4[((j0 + jj) * 256 + i) * 2];  // W[j][i][0..3]
    o[jj * 4 + 0] = f2bf(wv.x); o[jj * 4 + 1] = f2bf(wv.y);
    o[jj * 4 + 2] = f2bf(wv.z); o[jj * 4 + 3] = 0;
  }
  *(bf16x8*)&Bp[(size_t)gid * 8] = o;
}

// ---------------------------------------------------------------------------
// prep_A: x (f32, 67MB) -> frag-ready bf16 A image (16.8MB, L3/L2-resident).
// Layout: A[row 8192][j 256][comp4 {0,1,2,4}] bf16 -> row stride 1024 shorts;
// an MFMA A-frag for lane (ln,qq), k-slice it is the contiguous 16B at
// row*1024 + it*32 + qq*8. Thread = 2 j-granules: read 64B coalesced,
// write 16B coalesced. R4 measured this exact shape at ~6.2 TB/s.
// ---------------------------------------------------------------------------
__global__ __launch_bounds__(256) void ga_prep_A(const float* __restrict__ x,
                                                 short* __restrict__ A) {
  const int g = blockIdx.x * 256 + threadIdx.x;  // 1,048,576 = 8192 rows * 128 jp
  const float4* xp = (const float4*)x + (size_t)g * 4;
  const float4 a0 = xp[0], a1 = xp[1], b0 = xp[2], b1 = xp[3];
  bf16x8 o;
  o[0] = f2bf(a0.x); o[1] = f2bf(a0.y); o[2] = f2bf(a0.z); o[3] = f2bf(a1.x);
  o[4] = f2bf(b0.x); o[5] = f2bf(b0.y); o[6] = f2bf(b0.z); o[7] = f2bf(b1.x);
  *(bf16x8*)&A[(size_t)g * 8] = o;
}

// ---------------------------------------------------------------------------
// gemm: 2048 blocks (512 row-tiles x 4 col-blocks) x 256 threads (4 waves).
// NO LDS, NO BARRIERS anywhere. Wave = 16 rows x col-group cg (16 c0-cols +
// their 16 c4 partners). Per iter: A-frag from L3-hot A image (global),
// B-frag from L2-hot Bp (global), both depth-4 register pipelines; build
// c4 frag in-register; 2 MFMA. Epilogue: direct per-lane full-multivector
// nontemporal stores (bias + c0 at comp0, + c4 at comp4) - no staging.
// ~60 VGPR, 0 LDS -> 6 blocks/CU: 24 independent waves/CU at different
// pipeline phases (the fills' elastic regime), vs 16 lockstep before.
// ---------------------------------------------------------------------------
__global__ __launch_bounds__(256, 6) void ga_gemm(
    const short* __restrict__ A, const short* __restrict__ Bp,
    const float* __restrict__ bias, float* __restrict__ y) {
  const int t = threadIdx.x, lane = t & 63, w = t >> 6;
  const int ln = lane & 15, qq = lane >> 4;
  const int bm = blockIdx.x >> 2, cb = blockIdx.x & 3;
  const int R0 = bm * 16, cg = cb * 4 + w;
  const int i = cg * 16 + ln;  // output col (c0) / +256 (c4)

  const short* ap = A + (size_t)(R0 + ln) * 1024 + qq * 8;
  const short* bp = Bp + (size_t)cg * 512 + lane * 8;

  bf16x8 Af[4], Bf[4];
#define LA(it, b) { Af[b] = *(const bf16x8*)(ap + (it) * 32); }
#define LB(it, b) { Bf[b] = *(const bf16x8*)(bp + (size_t)(it) * 8192); }
  LA(0, 0) LA(1, 1) LA(2, 2) LA(3, 3)
  LB(0, 0) LB(1, 1) LB(2, 2) LB(3, 3)

  f32x4 acc0 = {}, acc1 = {};
#pragma unroll
  for (int it = 0; it < 32; ++it) {
    const bf16x8 af = Af[it & 3];
    const bf16x8 F = Bf[it & 3];
    const u32x4 fu = __builtin_bit_cast(u32x4, F);
    u32x4 gu;
    gu.x = fu.y << 16;                               // [0, w2]
    gu.y = ((fu.x >> 16) | (fu.x << 16)) ^ 0x8000u;  // [-w1, w0]
    gu.z = fu.w << 16;
    gu.w = ((fu.z >> 16) | (fu.z << 16)) ^ 0x8000u;
    const bf16x8 G = __builtin_bit_cast(bf16x8, gu);
    acc0 = __builtin_amdgcn_mfma_f32_16x16x32_bf16(af, F, acc0, 0, 0, 0);
    acc1 = __builtin_amdgcn_mfma_f32_16x16x32_bf16(af, G, acc1, 0, 0, 0);
    if (it + 4 < 32) { LA(it + 4, it & 3) LB(it + 4, it & 3) }
  }

  // ---- epilogue: C/D layout col = ln, row = qq*4 + r (verified r0-r8) ----
  const f32x4 bv0 = ((const f32x4*)bias)[i * 2];      // bias[i][0..3]
  const f32x4 bv1 = ((const f32x4*)bias)[i * 2 + 1];  // bias[i][4..7]
  f32x4* yp = (f32x4*)y + ((size_t)(R0 + qq * 4) * 256 + i) * 2;
#pragma unroll
  for (int r = 0; r < 4; ++r) {
    f32x4 o0 = bv0, o1 = bv1;
    o0[0] += acc0[r];  // c0 -> comp 0
    o1[0] += acc1[r];  // c4 -> comp 4
    __builtin_nontemporal_store(o0, yp + (size_t)r * 512);
    __builtin_nontemporal_store(o1, yp + (size_t)r * 512 + 1);
  }
}

extern "C" void kernel_launch(void* const* d_in, const int* in_sizes, int n_in,
                              void* d_out, int out_size, void* d_ws, size_t ws_size,
                              hipStream_t stream) {
  const float* x = (const float*)d_in[0];
  const float* W = (const float*)d_in[1];
  const float* bias = (const float*)d_in[2];
  float* y = (float*)d_out;
  short* Bp = (short*)d_ws;                  // 512 KB (c0 half only)
  short* A = (short*)d_ws + (1 << 18);       // 16.8 MB bf16 A image

  ga_prep_B<<<dim3(128), dim3(256), 0, stream>>>(W, Bp);
  ga_prep_A<<<dim3(4096), dim3(256), 0, stream>>>(x, A);
  ga_gemm<<<dim3(2048), dim3(256), 0, stream>>>(A, Bp, bias, y);
}